// Round 9
// baseline (103.556 us; speedup 1.0000x reference)
//
#include <hip/hip_runtime.h>
#include <stdint.h>

typedef _Float16 half8  __attribute__((ext_vector_type(8)));
typedef float    floatx4 __attribute__((ext_vector_type(4)));
typedef uint32_t uint4v  __attribute__((ext_vector_type(4)));

#define KDIM   4096
#define ODIM   11008
#define NG     32
#define KSPLIT 8
#define GPB    4        // groups (128 k) per k-chunk: 512 k per block
#define OBLK   172      // o-blocks of 64 columns

__global__ void zero_out_kernel(float4* __restrict__ out) {
    out[(size_t)blockIdx.x * 256 + threadIdx.x] = float4{0.f, 0.f, 0.f, 0.f};
}

__device__ __forceinline__ uint32_t pk_f16(float a, float b) {
    return __builtin_bit_cast(uint32_t, __builtin_amdgcn_cvt_pkrtz(a, b));
}

// x fp32 [64][4096] -> f16 fragments in xh2[g][ks][mt][lane] (uint4 each,
// halves slot-paired (x_j, x_{j+4})), plus per-(group,m) row sums xsumT[32][64].
// For chunk c (8 k) of row m: g=c>>4, q=(c&15)>>2, ks=c&3, mt=m>>4, ml=m&15;
// fragment lane = q*16+ml. Conversion exact (x is fp32-upcast fp16).
__global__ __launch_bounds__(256) void cvt_x_kernel(
    const float4* __restrict__ x, uint4v* __restrict__ xh2,
    float* __restrict__ xsumT)
{
    const int i = blockIdx.x * 256 + threadIdx.x;   // chunk id 0..32767
    const float4 f0 = x[2 * i];
    const float4 f1 = x[2 * i + 1];
    const uint4v v = {pk_f16(f0.x, f1.x), pk_f16(f0.y, f1.y),
                      pk_f16(f0.z, f1.z), pk_f16(f0.w, f1.w)};
    const int m  = i >> 9, c = i & 511;
    const int g  = c >> 4, cg = c & 15, q = cg >> 2, ks = cg & 3;
    const int mt = m >> 4, ml = m & 15;
    xh2[((size_t)(g * 4 + ks) * 4 + mt) * 64 + q * 16 + ml] = v;

    float p = f0.x + f0.y + f0.z + f0.w + f1.x + f1.y + f1.z + f1.w;
    p += __shfl_xor(p, 1);
    p += __shfl_xor(p, 2);
    p += __shfl_xor(p, 4);
    p += __shfl_xor(p, 8);
    if ((threadIdx.x & 15) == 0) xsumT[g * 64 + m] = p;
}

// Block: 256 thr = 4 waves, NO LDS, NO barriers. Wave wv owns 16 o-cols
// (o0+wv*16..+15) x all 64 m (4 M-tiles). Per group: ONE qweight uint4/lane
// (unique per wave) -> B frags reused across 4 M-tiles; A frags stream from
// xh2 (L1-shared across waves). Zero-point via epilogue rowsum correction;
// k-chunks combine via atomicAdd (out pre-zeroed).
__global__ __launch_bounds__(256, 4) void w4a16_kernel(
    const uint4v*   __restrict__ xh2,    // [32][4][4][64] uint4
    const uint4v*   __restrict__ qw,     // [11008][128] uint4
    const uint32_t* __restrict__ qz,     // [11008][4]
    const float*    __restrict__ sc,     // [11008][32] (fp32-upcast fp16)
    const float*    __restrict__ xsumT,  // [32][64]
    float*          __restrict__ out)    // [64][11008]
{
    const int t    = threadIdx.x;
    const int wv   = t >> 6;
    const int lane = t & 63;
    const int q    = lane >> 4;
    const int ml   = lane & 15;

    const int ob = blockIdx.x % OBLK;
    const int kb = blockIdx.x / OBLK;
    const int o0 = ob * 64;
    const int g0 = kb * GPB;
    const int o  = o0 + wv * 16 + ml;    // this lane's o column (B col = ml)

    // prefetch the block's entire qweight need: GPB uint4 per lane
    const uint4v* qwp = qw + (size_t)o * 128 + g0 * 4 + q;
    uint4v u[GPB];
    #pragma unroll
    for (int g = 0; g < GPB; ++g) u[g] = qwp[g * 4];

    const uint32_t zdw  = qz[(size_t)o * 4 + (g0 >> 3)];
    const floatx4  svec = *reinterpret_cast<const floatx4*>(sc + (size_t)o * NG + g0);
    const int      zsh0 = (g0 & 7) * 4;

    const uint4v* xp = xh2 + (size_t)g0 * 1024 + lane;

    floatx4 acc[4] = {{0.f,0.f,0.f,0.f},{0.f,0.f,0.f,0.f},
                      {0.f,0.f,0.f,0.f},{0.f,0.f,0.f,0.f}};
    float czs[GPB];

    #pragma unroll
    for (int g = 0; g < GPB; ++g) {
        const uint32_t zn = (zdw >> (zsh0 + g * 4)) & 0xFu;
        const float    s  = svec[g];
        czs[g] = s * (1024.0f + (float)zn);

        floatx4 tmp[4] = {{0.f,0.f,0.f,0.f},{0.f,0.f,0.f,0.f},
                          {0.f,0.f,0.f,0.f},{0.f,0.f,0.f,0.f}};
        #pragma unroll
        for (int ks = 0; ks < 4; ++ks) {
            const uint32_t ud = u[g][ks];
            // B frag: halves are exact fp16 (1024 + nibble), slot pairs (j, j+4)
            const uint4v bw = {
                ( ud         & 0x000F000Fu) | 0x64006400u,
                ((ud >> 4)   & 0x000F000Fu) | 0x64006400u,
                ((ud >> 8)   & 0x000F000Fu) | 0x64006400u,
                ((ud >> 12)  & 0x000F000Fu) | 0x64006400u};
            const half8 b = __builtin_bit_cast(half8, bw);
            #pragma unroll
            for (int mt = 0; mt < 4; ++mt) {
                const half8 a = __builtin_bit_cast(half8,
                    xp[(size_t)g * 1024 + ks * 256 + mt * 64]);
                tmp[mt] = __builtin_amdgcn_mfma_f32_16x16x32_f16(a, b, tmp[mt], 0, 0, 0);
            }
        }
        #pragma unroll
        for (int mt = 0; mt < 4; ++mt)
            #pragma unroll
            for (int r = 0; r < 4; ++r)
                acc[mt][r] += s * tmp[mt][r];
    }

    // epilogue: zero-point correction + atomic accumulate
    // C/D: col = ml (o), row = q*4 + r within tile mt -> m = mt*16 + q*4 + r
    #pragma unroll
    for (int mt = 0; mt < 4; ++mt) {
        floatx4 corr = {0.f, 0.f, 0.f, 0.f};
        #pragma unroll
        for (int g = 0; g < GPB; ++g) {
            const floatx4 xs = *reinterpret_cast<const floatx4*>(
                xsumT + (g0 + g) * 64 + mt * 16 + q * 4);
            #pragma unroll
            for (int r = 0; r < 4; ++r) corr[r] += czs[g] * xs[r];
        }
        float* op = out + (size_t)(mt * 16 + q * 4) * ODIM + o;
        #pragma unroll
        for (int r = 0; r < 4; ++r)
            atomicAdd(op + (size_t)r * ODIM, acc[mt][r] - corr[r]);
    }
}

extern "C" void kernel_launch(void* const* d_in, const int* in_sizes, int n_in,
                              void* d_out, int out_size, void* d_ws, size_t ws_size,
                              hipStream_t stream) {
    const float*    x       = (const float*)d_in[0];
    const uint32_t* qweight = (const uint32_t*)d_in[1];
    const uint32_t* qzeros  = (const uint32_t*)d_in[2];
    const float*    scales  = (const float*)d_in[3];
    float* out = (float*)d_out;

    uint4v* xh2   = (uint4v*)d_ws;                         // 512 KB
    float*  xsumT = (float*)((char*)d_ws + 512 * 1024);    // 8 KB

    cvt_x_kernel<<<dim3(128), dim3(256), 0, stream>>>((const float4*)x, xh2, xsumT);
    zero_out_kernel<<<dim3(688), dim3(256), 0, stream>>>((float4*)out);
    w4a16_kernel<<<dim3(OBLK * KSPLIT), dim3(256), 0, stream>>>(
        xh2, (const uint4v*)qweight, qzeros, scales, xsumT, out);
}

// Round 10
// 97.808 us; speedup vs baseline: 1.0588x; 1.0588x over previous
//
#include <hip/hip_runtime.h>
#include <stdint.h>

typedef _Float16 half8  __attribute__((ext_vector_type(8)));
typedef float    floatx4 __attribute__((ext_vector_type(4)));
typedef uint32_t uint4v  __attribute__((ext_vector_type(4)));

#define KDIM   4096
#define ODIM   11008
#define NG     32
#define KSPLIT 4
#define GPB    8        // groups (128 k) per k-chunk: 1024 k per block
#define OBLK   172      // o-blocks of 64 columns -> 688 blocks total
#define PITCH  20       // LDS dwords per o-row slice: 16 data + 4 pad
#define PART_ELEMS (64 * ODIM)   // 704512 floats per k-partial

__device__ __forceinline__ uint32_t pk_f16(float a, float b) {
    return __builtin_bit_cast(uint32_t, __builtin_amdgcn_cvt_pkrtz(a, b));
}

// x fp32 [64][4096] -> f16 fragments xh2[g][ks][mt][lane] (uint4, halves
// slot-paired (x_j, x_{j+4})) + per-(group,m) row sums xsumT[32][64].
// chunk c of row m: g=c>>4, q=(c&15)>>2, ks=c&3, mt=m>>4, ml=m&15, lane=q*16+ml.
__global__ __launch_bounds__(256) void cvt_x_kernel(
    const float4* __restrict__ x, uint4v* __restrict__ xh2,
    float* __restrict__ xsumT)
{
    const int i = blockIdx.x * 256 + threadIdx.x;   // chunk id 0..32767
    const float4 f0 = x[2 * i];
    const float4 f1 = x[2 * i + 1];
    const uint4v v = {pk_f16(f0.x, f1.x), pk_f16(f0.y, f1.y),
                      pk_f16(f0.z, f1.z), pk_f16(f0.w, f1.w)};
    const int m  = i >> 9, c = i & 511;
    const int g  = c >> 4, cg = c & 15, q = cg >> 2, ks = cg & 3;
    const int mt = m >> 4, ml = m & 15;
    xh2[((size_t)(g * 4 + ks) * 4 + mt) * 64 + q * 16 + ml] = v;

    float p = f0.x + f0.y + f0.z + f0.w + f1.x + f1.y + f1.z + f1.w;
    p += __shfl_xor(p, 1);
    p += __shfl_xor(p, 2);
    p += __shfl_xor(p, 4);
    p += __shfl_xor(p, 8);
    if ((threadIdx.x & 15) == 0) xsumT[g * 64 + m] = p;
}

// out = sum of KSPLIT partials; 172 blocks, grid-stride (4 float4/thread)
__global__ __launch_bounds__(256) void reduce_kernel(
    const float4* __restrict__ part, float4* __restrict__ out)
{
    const int NT = OBLK * 256;                        // 44032
    for (int i = blockIdx.x * 256 + threadIdx.x;
         i < PART_ELEMS / 4; i += NT) {
        float4 a = part[i];
        #pragma unroll
        for (int kb = 1; kb < KSPLIT; ++kb) {
            const float4 b = part[(size_t)kb * (PART_ELEMS / 4) + i];
            a.x += b.x; a.y += b.y; a.z += b.z; a.w += b.w;
        }
        out[i] = a;
    }
}

// Block: 256 thr = 4 waves. Wave wv: M-tile wv (16 m) x 64 o-cols (4 subtiles).
// qweight deduped via double-buffered LDS (all 256 threads stage 64 rows x 64 B
// per group); x read from fragment-ordered xh2 (full-line touches, unique per
// wave). Plain stores to per-k-chunk partials (no atomics).
__global__ __launch_bounds__(256, 2) void w4a16_kernel(
    const uint4v*   __restrict__ xh2,    // [32][4][4][64] uint4
    const uint32_t* __restrict__ qw,     // [11008][512] dwords
    const uint32_t* __restrict__ qz,     // [11008][4]
    const float*    __restrict__ sc,     // [11008][32] (fp32-upcast fp16)
    const float*    __restrict__ xsumT,  // [32][64]
    float*          __restrict__ part)   // [KSPLIT][64][11008]
{
    __shared__ uint32_t qlds[2][64 * PITCH];   // 2 x 5120 B

    const int t    = threadIdx.x;
    const int wv   = t >> 6;
    const int lane = t & 63;
    const int q    = lane >> 4;
    const int ml   = lane & 15;

    const int ob = blockIdx.x % OBLK;
    const int kb = blockIdx.x / OBLK;
    const int o0 = ob * 64;
    const int g0 = kb * GPB;             // 0,8,16,24

    // qweight staging: thread t -> o-row t>>2, 16-B chunk t&3
    const int srow = t >> 2;
    const int schk = t & 3;
    const uint32_t* sgp = qw + (size_t)(o0 + srow) * 512 + g0 * 16 + schk * 4;
    const int widx = srow * PITCH + schk * 4;

    // x fragments: wave-owned m-tile, fragment-ordered (1 KB/instruction)
    const uint4v* xp = xh2 + (size_t)(g0 * 16 + wv) * 64 + lane;

    // prologue: per-subtile zeros dword (8 nibbles = our 8 groups) + scales
    uint32_t zdw[4];
    floatx4  svec[4][2];
    #pragma unroll
    for (int sub = 0; sub < 4; ++sub) {
        const int o = o0 + sub * 16 + ml;
        zdw[sub]     = qz[(size_t)o * 4 + kb];
        svec[sub][0] = *reinterpret_cast<const floatx4*>(sc + (size_t)o * NG + g0);
        svec[sub][1] = *reinterpret_cast<const floatx4*>(sc + (size_t)o * NG + g0 + 4);
    }

    const int mrow = wv * 16 + q * 4;
    floatx4 acc[4] = {{0.f,0.f,0.f,0.f},{0.f,0.f,0.f,0.f},
                      {0.f,0.f,0.f,0.f},{0.f,0.f,0.f,0.f}};

    // prime the pipeline: qweight stage g=0 + x frags g=0
    uint4v sv = *reinterpret_cast<const uint4v*>(sgp);
    uint4v ax[2][4];
    #pragma unroll
    for (int ks = 0; ks < 4; ++ks) ax[0][ks] = xp[ks * 256];

    #pragma unroll
    for (int g = 0; g < GPB; ++g) {
        *reinterpret_cast<uint4v*>(&qlds[g & 1][widx]) = sv;
        __syncthreads();
        // issue next-group loads right after the barrier (overlap compute g)
        if (g + 1 < GPB) {
            sv = *reinterpret_cast<const uint4v*>(sgp + (g + 1) * 16);
            #pragma unroll
            for (int ks = 0; ks < 4; ++ks)
                ax[(g + 1) & 1][ks] = xp[(size_t)(g + 1) * 1024 + ks * 256];
        }

        half8 afrag[4];
        #pragma unroll
        for (int ks = 0; ks < 4; ++ks)
            afrag[ks] = __builtin_bit_cast(half8, ax[g & 1][ks]);

        uint4v qf[4];
        #pragma unroll
        for (int sub = 0; sub < 4; ++sub)
            qf[sub] = *reinterpret_cast<const uint4v*>(
                &qlds[g & 1][(sub * 16 + ml) * PITCH + q * 4]);

        // per-group row-sum slice for zero-point correction (one 64-B line)
        const floatx4 xsg = *reinterpret_cast<const floatx4*>(
            xsumT + (g0 + g) * 64 + mrow);

        #pragma unroll
        for (int sub = 0; sub < 4; ++sub) {
            const uint32_t zn  = (zdw[sub] >> (g * 4)) & 0xFu;
            const float    s   = svec[sub][g >> 2][g & 3];
            const float    czs = s * (1024.0f + (float)zn);

            floatx4 tmp = {0.f, 0.f, 0.f, 0.f};
            #pragma unroll
            for (int ks = 0; ks < 4; ++ks) {
                const uint32_t ud = qf[sub][ks];
                const uint4v bw = {
                    ( ud         & 0x000F000Fu) | 0x64006400u,
                    ((ud >> 4)   & 0x000F000Fu) | 0x64006400u,
                    ((ud >> 8)   & 0x000F000Fu) | 0x64006400u,
                    ((ud >> 12)  & 0x000F000Fu) | 0x64006400u};
                const half8 b = __builtin_bit_cast(half8, bw);
                tmp = __builtin_amdgcn_mfma_f32_16x16x32_f16(afrag[ks], b, tmp, 0, 0, 0);
            }
            #pragma unroll
            for (int r = 0; r < 4; ++r)
                acc[sub][r] += s * tmp[r] - czs * xsg[r];
        }
    }

    // epilogue: coalesced stores to this k-chunk's partial
    float* pb = part + (size_t)kb * PART_ELEMS + (size_t)mrow * ODIM;
    #pragma unroll
    for (int sub = 0; sub < 4; ++sub) {
        float* op = pb + o0 + sub * 16 + ml;
        op[0]                = acc[sub][0];
        op[(size_t)ODIM]     = acc[sub][1];
        op[2 * (size_t)ODIM] = acc[sub][2];
        op[3 * (size_t)ODIM] = acc[sub][3];
    }
}

extern "C" void kernel_launch(void* const* d_in, const int* in_sizes, int n_in,
                              void* d_out, int out_size, void* d_ws, size_t ws_size,
                              hipStream_t stream) {
    const float*    x       = (const float*)d_in[0];
    const uint32_t* qweight = (const uint32_t*)d_in[1];
    const uint32_t* qzeros  = (const uint32_t*)d_in[2];
    const float*    scales  = (const float*)d_in[3];
    float* out = (float*)d_out;

    uint4v* xh2   = (uint4v*)d_ws;                         // 512 KB
    float*  xsumT = (float*)((char*)d_ws + 512 * 1024);    // 8 KB
    float*  part  = (float*)((char*)d_ws + 1024 * 1024);   // 11.3 MB

    cvt_x_kernel<<<dim3(128), dim3(256), 0, stream>>>((const float4*)x, xh2, xsumT);
    w4a16_kernel<<<dim3(OBLK * KSPLIT), dim3(256), 0, stream>>>(
        xh2, qweight, qzeros, scales, xsumT, part);
    reduce_kernel<<<dim3(OBLK), dim3(256), 0, stream>>>(
        (const float4*)part, (float4*)out);
}